// Round 6
// baseline (2927.428 us; speedup 1.0000x reference)
//
#include <hip/hip_runtime.h>
#include <hip/hip_bf16.h>
#include <math.h>

#define BB 32
#define SS 256
#define EE 512
#define HH 1024
#define LDM 256
#define NROW (BB*SS)   // 8192

typedef __attribute__((ext_vector_type(8))) short bf16x8;
typedef __attribute__((ext_vector_type(4))) float f32x4;

static __device__ inline unsigned short f2bf(float f){
  unsigned u = __float_as_uint(f);
  unsigned r = (u + 0x7fffu + ((u >> 16) & 1u)) >> 16;
  return (unsigned short)r;
}
static __device__ inline unsigned short f2bf_fast(float f){
  return (unsigned short)((__float_as_uint(f) + 0x8000u) >> 16);
}
static __device__ inline bf16x8 cvt8(float4 x, float4 y){
  union { ushort s[8]; bf16x8 v; } t;
  t.s[0]=f2bf_fast(x.x); t.s[1]=f2bf_fast(x.y); t.s[2]=f2bf_fast(x.z); t.s[3]=f2bf_fast(x.w);
  t.s[4]=f2bf_fast(y.x); t.s[5]=f2bf_fast(y.y); t.s[6]=f2bf_fast(y.z); t.s[7]=f2bf_fast(y.w);
  return t.v;
}
static __device__ inline float ftanh(float x){
  float e = __expf(2.f*x);
  return 1.f - 2.f/(e + 1.f);
}
// LLC-direct (agent-coherent) 16B fragment load as 2x8B relaxed atomics.
static __device__ inline bf16x8 ld_frag(const unsigned long long* p){
  union { unsigned long long u[2]; bf16x8 v; } t;
  t.u[0] = __hip_atomic_load((unsigned long long*)p,     __ATOMIC_RELAXED, __HIP_MEMORY_SCOPE_AGENT);
  t.u[1] = __hip_atomic_load((unsigned long long*)p + 1, __ATOMIC_RELAXED, __HIP_MEMORY_SCOPE_AGENT);
  return t.v;
}

// ---------------- sort (stable argsort by descending length) ----------------
__global__ void k_sort(const int* __restrict__ length, int* __restrict__ sorted_idx){
  int b = threadIdx.x;
  if (b >= BB) return;
  int lb = length[b];
  int r = 0;
  for (int o = 0; o < BB; ++o){
    int lo = length[o];
    if (lo > lb || (lo == lb && o < b)) ++r;
  }
  sorted_idx[r] = b;
}

__global__ void k_maps(const int* __restrict__ sorted_idx,
                       const int* __restrict__ inp_seq, const int* __restrict__ tgt_seq,
                       int* __restrict__ tokmap, int* __restrict__ tgtmap){
  int bs = blockIdx.x; int t = threadIdx.x;
  int b = sorted_idx[bs];
  tokmap[bs*SS + t] = inp_seq[b*SS + t];
  tgtmap[bs*SS + t] = tgt_seq[b*SS + t];
}

// hid = z @ l2h_w.T + l2h_b, written in bf16 fragment-major layout
__global__ __launch_bounds__(256) void k_hid(const float* __restrict__ z,
        const float* __restrict__ w, const float* __restrict__ bias,
        ushort* __restrict__ hb0){
  int id = blockIdx.x*256 + threadIdx.x;
  int b = id >> 11, c = id & 2047;
  const float4* zr = (const float4*)(z + b*LDM);
  const float4* wr = (const float4*)(w + (size_t)c*LDM);
  float a0=0,a1=0,a2=0,a3=0;
  #pragma unroll 4
  for (int k=0;k<LDM/4;k++){ float4 zz=zr[k], ww=wr[k];
    a0+=zz.x*ww.x; a1+=zz.y*ww.y; a2+=zz.z*ww.z; a3+=zz.w*ww.w; }
  float val = a0+a1+a2+a3 + bias[c];
  int layer = id >> 15, bp = (id >> 10) & 31, j = id & 1023;
  hb0[(layer<<15) + ((j>>3)<<8) + (bp<<3) + (j&7)] = f2bf(val);
}

// ---------------- bf16 MFMA GEMM (128x128 tile, BK=64) ----------------
__global__ __launch_bounds__(256) void k_gemm_bf16(
    const float* __restrict__ A, int lda, const int* __restrict__ rowmap,
    const float* __restrict__ Bm,
    const float* __restrict__ bias0, const float* __restrict__ bias1,
    float* __restrict__ C, int M, int N, int K)
{
  __shared__ ushort As[128*72];
  __shared__ ushort Bs[128*72];
  const int nt = blockIdx.x * 128, mt = blockIdx.y * 128;
  const int tid = threadIdx.x;
  const int wv = tid >> 6, ln = tid & 63;
  const int wm = wv & 1, wn = wv >> 1;
  const int lc = ln & 15, quad = ln >> 4;
  f32x4 acc[4][4] = {{{0.f,0.f,0.f,0.f}}};

  for (int s = 0; s < K; s += 64){
    __syncthreads();
    #pragma unroll
    for (int cc = 0; cc < 4; ++cc){
      int ch = tid*4 + cc;
      int r = ch >> 3, c = ch & 7;
      int ar = mt + r;
      const float* ap = A + (size_t)(rowmap ? rowmap[ar] : ar)*lda + s + c*8;
      float4 x = *(const float4*)ap, y = *(const float4*)(ap+4);
      *(bf16x8*)&As[r*72 + c*8] = cvt8(x, y);
      int br = nt + r; if (br >= N) br = N - 1;
      const float* bp = Bm + (size_t)br*K + s + c*8;
      float4 bx = *(const float4*)bp, by = *(const float4*)(bp+4);
      *(bf16x8*)&Bs[r*72 + c*8] = cvt8(bx, by);
    }
    __syncthreads();
    #pragma unroll
    for (int kq = 0; kq < 2; ++kq){
      int cq = kq*4 + quad;
      bf16x8 af[4], bfv[4];
      #pragma unroll
      for (int i=0;i<4;i++) af[i]  = *(const bf16x8*)&As[(wm*64 + i*16 + lc)*72 + cq*8];
      #pragma unroll
      for (int j=0;j<4;j++) bfv[j] = *(const bf16x8*)&Bs[(wn*64 + j*16 + lc)*72 + cq*8];
      #pragma unroll
      for (int i=0;i<4;i++)
        #pragma unroll
        for (int j=0;j<4;j++)
          acc[i][j] = __builtin_amdgcn_mfma_f32_16x16x32_bf16(af[i], bfv[j], acc[i][j], 0, 0, 0);
    }
  }
  #pragma unroll
  for (int j=0;j<4;j++){
    int col = nt + wn*64 + j*16 + lc;
    if (col < N){
      float badd = (bias0 ? bias0[col] : 0.f) + (bias1 ? bias1[col] : 0.f);
      #pragma unroll
      for (int i=0;i<4;i++){
        int row = mt + wm*64 + i*16 + quad*4;
        #pragma unroll
        for (int r=0;r<4;r++)
          C[(size_t)(row+r)*N + col] = acc[i][j][r] + badd;
      }
    }
  }
}

// ---------------- fused 2-layer cooperative RNN, layer-1 one step behind ----
// 128 wgs: wg 0..63 = layer 0 (slice of W0hh), wg 64..127 = layer 1
// (slice of W1hh in LDS; W1ih streamed from L2 and fused into the same
// accumulation: pre1 = W1ih*h1[t], so the standalone pre1 GEMM disappears).
// Exchange slots (bf16 frag-major, LLC relaxed atomics):
//   E1 ping/pong at E+{0,32768}, E2 ping/pong at E+{65536,98304}.
// ctrA counts layer-0 step completions (64/step), ctrB layer-1.
__global__ __launch_bounds__(256) void k_rnn2(
    const float* __restrict__ pre0, float* __restrict__ h2out,
    const float* __restrict__ w0hh, const float* __restrict__ w1hh,
    const float* __restrict__ w1ih,
    const float* __restrict__ b1ih, const float* __restrict__ b1hh,
    const ushort* __restrict__ hb0, ushort* __restrict__ E,
    int* ctrA, int* ctrB)
{
  __shared__ ushort whhF[16384];      // [kblk][col][8] — frag order, 32 KB
  __shared__ float red[4*544];
  const int wg  = blockIdx.x;
  const bool L1 = wg >= 64;
  const int slice = L1 ? wg - 64 : wg;
  const int j0  = slice * 16;
  const int tid = threadIdx.x;

  const float* whh = L1 ? w1hh : w0hh;
  for (int c = tid; c < 4096; c += 256){
    int r = c >> 8, cc = (c & 255) * 4;
    float4 w4 = *(const float4*)&whh[(size_t)(j0 + r)*HH + cc];
    uint2 p;
    p.x = (unsigned)f2bf(w4.x) | ((unsigned)f2bf(w4.y) << 16);
    p.y = (unsigned)f2bf(w4.z) | ((unsigned)f2bf(w4.w) << 16);
    *(uint2*)&whhF[((cc >> 3)*16 + r)*8 + (cc & 7)] = p;
  }
  const int lane = tid & 63, wv = tid >> 6;
  const int col = lane & 15, quad = lane >> 4;
  const int ob = tid >> 3, oj = (tid << 1) & 15;

  float2 base;                        // L0: pre0[t] prefetch; L1: bias
  if (!L1) base = *(const float2*)&pre0[((size_t)ob*SS + 0)*HH + j0 + oj];
  else     base = make_float2(b1ih[j0+oj]   + b1hh[j0+oj],
                              b1ih[j0+oj+1] + b1hh[j0+oj+1]);
  __syncthreads();

  for (int t = 0; t < SS; ++t){
    // ---- wait (combined poll: both counters in one loop iteration) ----
    if (tid == 0){
      int ta = L1 ? 64*(t+1) : 64*t;
      int tb = L1 ? 64*t     : 64*(t-1);
      for(;;){
        int a = __hip_atomic_load(ctrA, __ATOMIC_RELAXED, __HIP_MEMORY_SCOPE_AGENT);
        int b = __hip_atomic_load(ctrB, __ATOMIC_RELAXED, __HIP_MEMORY_SCOPE_AGENT);
        if (a >= ta && b >= tb) break;
      }
    }
    __syncthreads();

    const ushort* srcOwn = (t == 0) ? hb0 + (L1 ? 32768 : 0)
                                    : E + (L1 ? 65536 : 0) + (1 - (t & 1)) * 32768;
    ushort* dst = E + (L1 ? 65536 : 0) + (t & 1) * 32768;
    const unsigned long long* s64 = (const unsigned long long*)srcOwn;

    // own-state A-frags (h1[t-1] for L0 / h2[t-1] for L1)
    bf16x8 a0f[8], a1f[8];
    #pragma unroll
    for (int ks = 0; ks < 8; ++ks){
      int kb = wv*32 + ks*4 + quad;
      const unsigned long long* p = s64 + (kb << 6) + (col << 1);
      a0f[ks] = ld_frag(p);
      a1f[ks] = ld_frag(p + 32);
    }
    f32x4 acc0 = {0.f,0.f,0.f,0.f}, acc1 = {0.f,0.f,0.f,0.f};

    if (L1){
      // h1[t] A-frags (from E1 slot t&1) + W1ih B-frags (L2-cached fp32->bf16)
      const unsigned long long* s1 = (const unsigned long long*)(E + (t & 1) * 32768);
      bf16x8 c0f[8], c1f[8], wif[8];
      #pragma unroll
      for (int ks = 0; ks < 8; ++ks){
        int kb = wv*32 + ks*4 + quad;
        const unsigned long long* p = s1 + (kb << 6) + (col << 1);
        c0f[ks] = ld_frag(p);
        c1f[ks] = ld_frag(p + 32);
        const float* wp = w1ih + (size_t)(j0 + col)*HH + kb*8;
        wif[ks] = cvt8(*(const float4*)wp, *(const float4*)(wp + 4));
      }
      #pragma unroll
      for (int ks = 0; ks < 8; ++ks){
        int kb = wv*32 + ks*4 + quad;
        bf16x8 bfr = *(const bf16x8*)&whhF[(kb*16 + col)*8];
        acc0 = __builtin_amdgcn_mfma_f32_16x16x32_bf16(a0f[ks], bfr, acc0, 0, 0, 0);
        acc1 = __builtin_amdgcn_mfma_f32_16x16x32_bf16(a1f[ks], bfr, acc1, 0, 0, 0);
      }
      #pragma unroll
      for (int ks = 0; ks < 8; ++ks){
        acc0 = __builtin_amdgcn_mfma_f32_16x16x32_bf16(c0f[ks], wif[ks], acc0, 0, 0, 0);
        acc1 = __builtin_amdgcn_mfma_f32_16x16x32_bf16(c1f[ks], wif[ks], acc1, 0, 0, 0);
      }
    } else {
      #pragma unroll
      for (int ks = 0; ks < 8; ++ks){
        int kb = wv*32 + ks*4 + quad;
        bf16x8 bfr = *(const bf16x8*)&whhF[(kb*16 + col)*8];
        acc0 = __builtin_amdgcn_mfma_f32_16x16x32_bf16(a0f[ks], bfr, acc0, 0, 0, 0);
        acc1 = __builtin_amdgcn_mfma_f32_16x16x32_bf16(a1f[ks], bfr, acc1, 0, 0, 0);
      }
    }

    #pragma unroll
    for (int r = 0; r < 4; ++r){
      red[wv*544 + (quad*4 + r)*17 + col]        = acc0[r];
      red[wv*544 + (16 + quad*4 + r)*17 + col]   = acc1[r];
    }
    __syncthreads();

    int ro = ob*17 + oj;
    float s0 = red[ro]   + red[544 + ro]   + red[1088 + ro]   + red[1632 + ro];
    float s1v = red[ro+1] + red[544 + ro+1] + red[1088 + ro+1] + red[1632 + ro+1];
    float v0 = ftanh(base.x + s0);
    float v1 = ftanh(base.y + s1v);
    int k = j0 + oj;
    unsigned pk = (unsigned)f2bf(v0) | ((unsigned)f2bf(v1) << 16);
    __hip_atomic_store((unsigned*)dst + ((k >> 3) << 7) + (ob << 2) + ((k & 7) >> 1),
                       pk, __ATOMIC_RELAXED, __HIP_MEMORY_SCOPE_AGENT);

    asm volatile("s_waitcnt vmcnt(0)" ::: "memory");
    __syncthreads();
    if (tid == 0)
      __hip_atomic_fetch_add(L1 ? ctrB : ctrA, 1, __ATOMIC_RELAXED, __HIP_MEMORY_SCOPE_AGENT);

    // off-critical-path tail
    if (!L1){
      int tn2 = (t + 1 < SS) ? t + 1 : t;
      base = *(const float2*)&pre0[((size_t)ob*SS + tn2)*HH + j0 + oj];
    } else {
      *(float2*)&h2out[((size_t)ob*SS + t)*HH + j0 + oj] = make_float2(v0, v1);
    }
  }
}

// ---------------- fused cluster logsumexp ----------------
__global__ __launch_bounds__(256) void k_cluster(
    const float* __restrict__ proj, int Kp,
    const float* __restrict__ W, int Nc,
    float* __restrict__ stats, int ci)
{
  __shared__ float ps[4][4][256];
  int lane = threadIdx.x & 63;
  int wvl  = threadIdx.x >> 6;
  int r0 = (blockIdx.x*4 + wvl) * 4;
  for (int r=0;r<4;r++)
    for (int k=lane;k<Kp;k+=64)
      ps[wvl][r][k] = proj[(size_t)(r0+r)*Kp + k];
  __syncthreads();
  float mx[4], sm[4];
  #pragma unroll
  for (int r=0;r<4;r++){ mx[r]=-1e30f; sm[r]=0.f; }
  for (int n=lane; n<Nc; n+=64){
    const float* wr = W + (size_t)n*Kp;
    float l[4]={0.f,0.f,0.f,0.f};
    for (int k=0;k<Kp;k+=4){
      float4 w4 = *(const float4*)(wr+k);
      #pragma unroll
      for (int r=0;r<4;r++){
        l[r] += w4.x*ps[wvl][r][k] + w4.y*ps[wvl][r][k+1]
              + w4.z*ps[wvl][r][k+2] + w4.w*ps[wvl][r][k+3];
      }
    }
    #pragma unroll
    for (int r=0;r<4;r++){
      float nm = fmaxf(mx[r], l[r]);
      sm[r] = sm[r]*__expf(mx[r]-nm) + __expf(l[r]-nm);
      mx[r] = nm;
    }
  }
  #pragma unroll
  for (int r=0;r<4;r++){
    for (int off=32; off; off>>=1){
      float om = __shfl_down(mx[r], off);
      float os = __shfl_down(sm[r], off);
      float nm = fmaxf(mx[r], om);
      sm[r] = sm[r]*__expf(mx[r]-nm) + os*__expf(om-nm);
      mx[r] = nm;
    }
    if (lane==0){
      stats[(size_t)(r0+r)*6 + ci*2 + 0] = mx[r];
      stats[(size_t)(r0+r)*6 + ci*2 + 1] = sm[r];
    }
  }
}

// ---------------- target logit for tail clusters ----------------
__global__ __launch_bounds__(256) void k_tlogit(
    const int* __restrict__ tgtmap,
    const float* __restrict__ proj0, const float* __restrict__ proj1, const float* __restrict__ proj2,
    const float* __restrict__ w0, const float* __restrict__ w1, const float* __restrict__ w2,
    float* __restrict__ tlogit)
{
  int lane = threadIdx.x & 63;
  int row = (blockIdx.x * 256 + threadIdx.x) >> 6;
  int tgt = tgtmap[row];
  float acc = 0.f;
  const float* pr = nullptr; const float* wr = nullptr; int Kp = 0;
  if      (tgt >= 1000){ pr = proj2 + (size_t)row*16;  wr = w2 + (size_t)(tgt-1000)*16;  Kp=16;  }
  else if (tgt >= 100) { pr = proj1 + (size_t)row*64;  wr = w1 + (size_t)(tgt-100)*64;   Kp=64;  }
  else if (tgt >= 30)  { pr = proj0 + (size_t)row*256; wr = w0 + (size_t)(tgt-30)*256;   Kp=256; }
  for (int k=lane; k<Kp; k+=64) acc += pr[k]*wr[k];
  for (int off=32; off; off>>=1) acc += __shfl_down(acc, off);
  if (lane==0) tlogit[row] = acc;
}

// ---------------- final: head LSE + assemble NLL, reduce ----------------
__global__ __launch_bounds__(256) void k_final(
    const float* __restrict__ head, const float* __restrict__ stats,
    const float* __restrict__ tlogit, const int* __restrict__ tgtmap,
    float* __restrict__ out)
{
  int row = blockIdx.x*256 + threadIdx.x;
  int tgt = tgtmap[row];
  float nll = 0.f;
  if (tgt != 0){
    const float* hrow = head + (size_t)row*33;
    float m = hrow[0];
    #pragma unroll
    for (int i=1;i<33;i++) m = fmaxf(m, hrow[i]);
    float s = 0.f;
    #pragma unroll
    for (int i=0;i<33;i++) s += __expf(hrow[i]-m);
    float lse = __logf(s) + m;
    int ci = (tgt>=1000) ? 2 : (tgt>=100) ? 1 : (tgt>=30) ? 0 : -1;
    if (ci < 0){
      nll = lse - hrow[tgt];
    } else {
      float cm = stats[(size_t)row*6 + ci*2 + 0];
      float cs = stats[(size_t)row*6 + ci*2 + 1];
      nll = lse - hrow[30+ci] + (__logf(cs) + cm - tlogit[row]);
    }
  }
  float v = nll;
  for (int off=32; off; off>>=1) v += __shfl_down(v, off);
  __shared__ float wsum[4];
  int lane = threadIdx.x & 63, wv = threadIdx.x >> 6;
  if (lane==0) wsum[wv] = v;
  __syncthreads();
  if (threadIdx.x==0) atomicAdd(out, wsum[0]+wsum[1]+wsum[2]+wsum[3]);
}

extern "C" void kernel_launch(void* const* d_in, const int* in_sizes, int n_in,
                              void* d_out, int out_size, void* d_ws, size_t ws_size,
                              hipStream_t stream)
{
  const float* z      = (const float*)d_in[0];
  const float* emb    = (const float*)d_in[1];
  const float* l2h_w  = (const float*)d_in[2];
  const float* l2h_b  = (const float*)d_in[3];
  const float* w0ih   = (const float*)d_in[4];
  const float* w0hh   = (const float*)d_in[5];
  const float* b0ih   = (const float*)d_in[6];
  const float* b0hh   = (const float*)d_in[7];
  const float* w1ih   = (const float*)d_in[8];
  const float* w1hh   = (const float*)d_in[9];
  const float* b1ih   = (const float*)d_in[10];
  const float* b1hh   = (const float*)d_in[11];
  const float* head_w = (const float*)d_in[12];
  const float* p0     = (const float*)d_in[13];
  const float* tw0    = (const float*)d_in[14];
  const float* p1     = (const float*)d_in[15];
  const float* tw1    = (const float*)d_in[16];
  const float* p2     = (const float*)d_in[17];
  const float* tw2    = (const float*)d_in[18];
  const int* inp_seq  = (const int*)d_in[19];
  const int* tgt_seq  = (const int*)d_in[20];
  const int* length   = (const int*)d_in[21];

  float* ws   = (float*)d_ws;
  ushort* hb0 = (ushort*)ws;                      // 65536 ushorts (h0, both layers)
  ushort* Ex  = hb0 + 65536;                      // 131072 ushorts (E1 x2, E2 x2)
  float* bufA = ws + 98304;                       // 8192*1024  pre0; later head/proj/stats
  float* bufB = bufA + (size_t)NROW*HH;           // 8192*1024  h2
  int*   ibuf = (int*)(bufB + (size_t)NROW*HH);
  int* sorted_idx = ibuf;                         // 32
  int* tokmap = ibuf + 32;                        // 8192
  int* tgtmap = tokmap + NROW;                    // 8192
  int* flags  = tgtmap + NROW;                    // 128 ints: ctrA@0, ctrB@64
  float* headL = bufA;                            // 8192*33
  float* proj0 = headL + (size_t)NROW*33;         // 8192*256
  float* proj1 = proj0 + (size_t)NROW*256;        // 8192*64
  float* proj2 = proj1 + (size_t)NROW*64;         // 8192*16
  float* stats = proj2 + (size_t)NROW*16;         // 8192*6
  float* tlog  = stats + (size_t)NROW*6;          // 8192

  float* outF = (float*)d_out;
  hipMemsetAsync(outF, 0, sizeof(float), stream);
  hipMemsetAsync(flags, 0, 128*sizeof(int), stream);

  k_sort<<<1, 32, 0, stream>>>(length, sorted_idx);
  k_maps<<<32, 256, 0, stream>>>(sorted_idx, inp_seq, tgt_seq, tokmap, tgtmap);
  k_hid<<<256, 256, 0, stream>>>(z, l2h_w, l2h_b, hb0);

  // pre0 = emb[tok] @ w0ih^T + b0ih + b0hh
  k_gemm_bf16<<<dim3(HH/128, NROW/128), 256, 0, stream>>>(emb, EE, tokmap, w0ih,
                                                          b0ih, b0hh, bufA, NROW, HH, EE);
  // fused 2-layer recurrence (layer-1 pipelined one step behind; pre1 folded in)
  k_rnn2<<<128, 256, 0, stream>>>(bufA, bufB, w0hh, w1hh, w1ih, b1ih, b1hh,
                                  hb0, Ex, flags, flags + 64);

  // head logits + tail projections (A = h2 fp32)
  k_gemm_bf16<<<dim3(1, NROW/128), 256, 0, stream>>>(bufB, HH, nullptr, head_w,
                                                     nullptr, nullptr, headL, NROW, 33, HH);
  k_gemm_bf16<<<dim3(2, NROW/128), 256, 0, stream>>>(bufB, HH, nullptr, p0,
                                                     nullptr, nullptr, proj0, NROW, 256, HH);
  k_gemm_bf16<<<dim3(1, NROW/128), 256, 0, stream>>>(bufB, HH, nullptr, p1,
                                                     nullptr, nullptr, proj1, NROW, 64, HH);
  k_gemm_bf16<<<dim3(1, NROW/128), 256, 0, stream>>>(bufB, HH, nullptr, p2,
                                                     nullptr, nullptr, proj2, NROW, 16, HH);

  k_cluster<<<NROW/16, 256, 0, stream>>>(proj0, 256, tw0, 70,    stats, 0);
  k_cluster<<<NROW/16, 256, 0, stream>>>(proj1, 64,  tw1, 900,   stats, 1);
  k_cluster<<<NROW/16, 256, 0, stream>>>(proj2, 16,  tw2, 19000, stats, 2);
  k_tlogit<<<NROW/4, 256, 0, stream>>>(tgtmap, proj0, proj1, proj2, tw0, tw1, tw2, tlog);
  k_final<<<NROW/256, 256, 0, stream>>>(headL, stats, tlog, tgtmap, outF);
}

// Round 7
// 2844.922 us; speedup vs baseline: 1.0290x; 1.0290x over previous
//
#include <hip/hip_runtime.h>
#include <hip/hip_bf16.h>
#include <math.h>

#define BB 32
#define SS 256
#define EE 512
#define HH 1024
#define LDM 256
#define NROW (BB*SS)   // 8192
#define NWG 32         // cooperative wgs for recurrence (32 cols each)
#define NCAT 369       // 33 head + 256 + 64 + 16 packed proj cols

typedef __attribute__((ext_vector_type(8))) short bf16x8;
typedef __attribute__((ext_vector_type(4))) float f32x4;

static __device__ inline unsigned short f2bf(float f){
  unsigned u = __float_as_uint(f);
  unsigned r = (u + 0x7fffu + ((u >> 16) & 1u)) >> 16;
  return (unsigned short)r;
}
static __device__ inline unsigned short f2bf_fast(float f){
  return (unsigned short)((__float_as_uint(f) + 0x8000u) >> 16);
}
static __device__ inline bf16x8 cvt8(float4 x, float4 y){
  union { ushort s[8]; bf16x8 v; } t;
  t.s[0]=f2bf_fast(x.x); t.s[1]=f2bf_fast(x.y); t.s[2]=f2bf_fast(x.z); t.s[3]=f2bf_fast(x.w);
  t.s[4]=f2bf_fast(y.x); t.s[5]=f2bf_fast(y.y); t.s[6]=f2bf_fast(y.z); t.s[7]=f2bf_fast(y.w);
  return t.v;
}
static __device__ inline float ftanh(float x){
  float e = __expf(2.f*x);
  return 1.f - 2.f/(e + 1.f);
}
// LLC-direct (agent-coherent) 16B fragment load as 2x8B relaxed atomics.
static __device__ inline bf16x8 ld_frag(const unsigned long long* p){
  union { unsigned long long u[2]; bf16x8 v; } t;
  t.u[0] = __hip_atomic_load((unsigned long long*)p,     __ATOMIC_RELAXED, __HIP_MEMORY_SCOPE_AGENT);
  t.u[1] = __hip_atomic_load((unsigned long long*)p + 1, __ATOMIC_RELAXED, __HIP_MEMORY_SCOPE_AGENT);
  return t.v;
}

// ---------------- sort (stable argsort by descending length) ----------------
__global__ void k_sort(const int* __restrict__ length, int* __restrict__ sorted_idx){
  int b = threadIdx.x;
  if (b >= BB) return;
  int lb = length[b];
  int r = 0;
  for (int o = 0; o < BB; ++o){
    int lo = length[o];
    if (lo > lb || (lo == lb && o < b)) ++r;
  }
  sorted_idx[r] = b;
}

__global__ void k_maps(const int* __restrict__ sorted_idx,
                       const int* __restrict__ inp_seq, const int* __restrict__ tgt_seq,
                       int* __restrict__ tokmap, int* __restrict__ tgtmap){
  int bs = blockIdx.x; int t = threadIdx.x;
  int b = sorted_idx[bs];
  tokmap[bs*SS + t] = inp_seq[b*SS + t];
  tgtmap[bs*SS + t] = tgt_seq[b*SS + t];
}

// hid = z @ l2h_w.T + l2h_b, written in bf16 fragment-major layout
__global__ __launch_bounds__(256) void k_hid(const float* __restrict__ z,
        const float* __restrict__ w, const float* __restrict__ bias,
        ushort* __restrict__ hb0){
  int id = blockIdx.x*256 + threadIdx.x;
  int b = id >> 11, c = id & 2047;
  const float4* zr = (const float4*)(z + b*LDM);
  const float4* wr = (const float4*)(w + (size_t)c*LDM);
  float a0=0,a1=0,a2=0,a3=0;
  #pragma unroll 4
  for (int k=0;k<LDM/4;k++){ float4 zz=zr[k], ww=wr[k];
    a0+=zz.x*ww.x; a1+=zz.y*ww.y; a2+=zz.z*ww.z; a3+=zz.w*ww.w; }
  float val = a0+a1+a2+a3 + bias[c];
  int layer = id >> 15, bp = (id >> 10) & 31, j = id & 1023;
  hb0[(layer<<15) + ((j>>3)<<8) + (bp<<3) + (j&7)] = f2bf(val);
}

// ---------------- bf16 MFMA GEMM (128x128 tile, BK=64) ----------------
__global__ __launch_bounds__(256) void k_gemm_bf16(
    const float* __restrict__ A, int lda, const int* __restrict__ rowmap,
    const float* __restrict__ Bm,
    const float* __restrict__ bias0, const float* __restrict__ bias1,
    float* __restrict__ C, int M, int N, int K)
{
  __shared__ ushort As[128*72];
  __shared__ ushort Bs[128*72];
  const int nt = blockIdx.x * 128, mt = blockIdx.y * 128;
  const int tid = threadIdx.x;
  const int wv = tid >> 6, ln = tid & 63;
  const int wm = wv & 1, wn = wv >> 1;
  const int lc = ln & 15, quad = ln >> 4;
  f32x4 acc[4][4] = {{{0.f,0.f,0.f,0.f}}};

  for (int s = 0; s < K; s += 64){
    __syncthreads();
    #pragma unroll
    for (int cc = 0; cc < 4; ++cc){
      int ch = tid*4 + cc;
      int r = ch >> 3, c = ch & 7;
      int ar = mt + r;
      const float* ap = A + (size_t)(rowmap ? rowmap[ar] : ar)*lda + s + c*8;
      float4 x = *(const float4*)ap, y = *(const float4*)(ap+4);
      *(bf16x8*)&As[r*72 + c*8] = cvt8(x, y);
      int br = nt + r; if (br >= N) br = N - 1;
      const float* bp = Bm + (size_t)br*K + s + c*8;
      float4 bx = *(const float4*)bp, by = *(const float4*)(bp+4);
      *(bf16x8*)&Bs[r*72 + c*8] = cvt8(bx, by);
    }
    __syncthreads();
    #pragma unroll
    for (int kq = 0; kq < 2; ++kq){
      int cq = kq*4 + quad;
      bf16x8 af[4], bfv[4];
      #pragma unroll
      for (int i=0;i<4;i++) af[i]  = *(const bf16x8*)&As[(wm*64 + i*16 + lc)*72 + cq*8];
      #pragma unroll
      for (int j=0;j<4;j++) bfv[j] = *(const bf16x8*)&Bs[(wn*64 + j*16 + lc)*72 + cq*8];
      #pragma unroll
      for (int i=0;i<4;i++)
        #pragma unroll
        for (int j=0;j<4;j++)
          acc[i][j] = __builtin_amdgcn_mfma_f32_16x16x32_bf16(af[i], bfv[j], acc[i][j], 0, 0, 0);
    }
  }
  #pragma unroll
  for (int j=0;j<4;j++){
    int col = nt + wn*64 + j*16 + lc;
    if (col < N){
      float badd = (bias0 ? bias0[col] : 0.f) + (bias1 ? bias1[col] : 0.f);
      #pragma unroll
      for (int i=0;i<4;i++){
        int row = mt + wm*64 + i*16 + quad*4;
        #pragma unroll
        for (int r=0;r<4;r++)
          C[(size_t)(row+r)*N + col] = acc[i][j][r] + badd;
      }
    }
  }
}

// ---------------- cooperative persistent RNN recurrence ----------------
// 32 wgs; wg owns cols j0..j0+31 of h (rows of Whh, bf16 in LDS frag order).
// Cross-wg h exchange via RELAXED+AGENT atomics (LLC-coherent, no L2 wb/inv).
// Step barrier: single monotonic atomicAdd counter (32 adds/step).
__global__ __launch_bounds__(256) void k_rnn_coop(
    float* __restrict__ buf, const float* __restrict__ whh,
    const ushort* __restrict__ hb0, ushort* __restrict__ hbP,
    int* ctr, int layer)
{
  __shared__ ushort whhF[32768];      // [kblk 0..127][col 0..31][8] — frag order, 64 KB
  __shared__ float red[4*1056];       // [wv][b 0..31][33] padded
  const int wg  = blockIdx.x;
  const int tid = threadIdx.x;
  const int j0  = wg * 32;

  for (int c = tid; c < 8192; c += 256){
    int r = c >> 8, cc = (c & 255) * 4;
    float4 w4 = *(const float4*)&whh[(size_t)(j0 + r)*HH + cc];
    uint2 p;
    p.x = (unsigned)f2bf(w4.x) | ((unsigned)f2bf(w4.y) << 16);
    p.y = (unsigned)f2bf(w4.z) | ((unsigned)f2bf(w4.w) << 16);
    *(uint2*)&whhF[((cc >> 3)*32 + r)*8 + (cc & 7)] = p;
  }
  const int lane = tid & 63, wv = tid >> 6;
  const int col = lane & 15, quad = lane >> 4;
  const ushort* src0 = hb0 + (layer << 15);

  // per-thread output quad: i=0,1 -> o=tid+i*256: b=o>>4, jj=(o&15)*2
  float2 pre[2];
  #pragma unroll
  for (int i=0;i<2;i++){
    int o = tid + i*256; int b = o>>4, jj = (o&15)*2;
    pre[i] = *(const float2*)&buf[((size_t)b*SS + 0)*HH + j0 + jj];
  }
  __syncthreads();

  for (int t = 0; t < SS; ++t){
    const ushort* src = (t == 0) ? src0 : hbP + (1 - (t & 1)) * 32768;
    ushort* dst = hbP + (t & 1) * 32768;
    const unsigned long long* s64 = (const unsigned long long*)src;

    // batch-issue all LLC-direct frag loads, then MFMA
    bf16x8 a0f[8], a1f[8];
    #pragma unroll
    for (int ks = 0; ks < 8; ++ks){
      int kb = wv*32 + ks*4 + quad;
      const unsigned long long* p = s64 + (kb << 6) + (col << 1);
      a0f[ks] = ld_frag(p);
      a1f[ks] = ld_frag(p + 32);
    }
    f32x4 acc[2][2] = {{{0.f,0.f,0.f,0.f}}};
    #pragma unroll
    for (int ks = 0; ks < 8; ++ks){
      int kb = wv*32 + ks*4 + quad;
      bf16x8 b0 = *(const bf16x8*)&whhF[(kb*32 + col)*8];        // cols j0+0..15
      bf16x8 b1 = *(const bf16x8*)&whhF[(kb*32 + 16 + col)*8];   // cols j0+16..31
      acc[0][0] = __builtin_amdgcn_mfma_f32_16x16x32_bf16(a0f[ks], b0, acc[0][0], 0, 0, 0);
      acc[0][1] = __builtin_amdgcn_mfma_f32_16x16x32_bf16(a0f[ks], b1, acc[0][1], 0, 0, 0);
      acc[1][0] = __builtin_amdgcn_mfma_f32_16x16x32_bf16(a1f[ks], b0, acc[1][0], 0, 0, 0);
      acc[1][1] = __builtin_amdgcn_mfma_f32_16x16x32_bf16(a1f[ks], b1, acc[1][1], 0, 0, 0);
    }
    // partials: red[wv][b][j], b = bg*16+quad*4+r, j = cg*16+col, pad 33
    #pragma unroll
    for (int bg = 0; bg < 2; ++bg)
      #pragma unroll
      for (int cg = 0; cg < 2; ++cg)
        #pragma unroll
        for (int r = 0; r < 4; ++r)
          red[wv*1056 + (bg*16 + quad*4 + r)*33 + cg*16 + col] = acc[bg][cg][r];
    __syncthreads();

    float vv[2][2];
    #pragma unroll
    for (int i = 0; i < 2; ++i){
      int o = tid + i*256; int b = o>>4, jj = (o&15)*2;
      int ro = b*33 + jj;
      float s0 = red[ro]   + red[1056+ro]   + red[2112+ro]   + red[3168+ro];
      float s1 = red[ro+1] + red[1056+ro+1] + red[2112+ro+1] + red[3168+ro+1];
      vv[i][0] = ftanh(pre[i].x + s0);
      vv[i][1] = ftanh(pre[i].y + s1);
      int k = j0 + jj;
      unsigned pk = (unsigned)f2bf(vv[i][0]) | ((unsigned)f2bf(vv[i][1]) << 16);
      __hip_atomic_store((unsigned*)dst + ((k >> 3) << 7) + (b << 2) + ((k & 7) >> 1),
                         pk, __ATOMIC_RELAXED, __HIP_MEMORY_SCOPE_AGENT);
    }
    // all threads' stores durable at LLC, then ONE counter bump per wg
    asm volatile("s_waitcnt vmcnt(0)" ::: "memory");
    __syncthreads();
    if (tid == 0)
      __hip_atomic_fetch_add(ctr, 1, __ATOMIC_RELAXED, __HIP_MEMORY_SCOPE_AGENT);

    // off-protocol (cached): fp32 h for later GEMMs + next pre prefetch
    int tn2 = (t + 1 < SS) ? t + 1 : t;
    #pragma unroll
    for (int i = 0; i < 2; ++i){
      int o = tid + i*256; int b = o>>4, jj = (o&15)*2;
      *(float2*)&buf[((size_t)b*SS + t)*HH + j0 + jj] = make_float2(vv[i][0], vv[i][1]);
      pre[i] = *(const float2*)&buf[((size_t)b*SS + tn2)*HH + j0 + jj];
    }
    if (tid == 0){
      int tv = (t + 1) * NWG;
      while (__hip_atomic_load(ctr, __ATOMIC_RELAXED, __HIP_MEMORY_SCOPE_AGENT) < tv) {}
    }
    asm volatile("" ::: "memory");
    __syncthreads();
  }
}

// ---------------- pack head_w/p0/p1/p2 rows into Bcat [369][1024] ----------------
__global__ __launch_bounds__(256) void k_pack(
    const float* __restrict__ head_w, const float* __restrict__ p0,
    const float* __restrict__ p1, const float* __restrict__ p2,
    float* __restrict__ Bcat)
{
  int j = blockIdx.x;
  const float* src;
  if      (j < 33)  src = head_w + (size_t)j*HH;
  else if (j < 289) src = p0 + (size_t)(j-33)*HH;
  else if (j < 353) src = p1 + (size_t)(j-289)*HH;
  else              src = p2 + (size_t)(j-353)*HH;
  *(float4*)&Bcat[(size_t)j*HH + threadIdx.x*4] = *(const float4*)&src[threadIdx.x*4];
}

// ---------------- cluster logsumexp + target logit, 16 rows/block ----------------
// proj rows live in packC (stride NCAT, at column offset `off`).
// W chunks staged in LDS (CH rows, padded stride Kp+4).
__global__ __launch_bounds__(256) void k_cluster2(
    const float* __restrict__ packC, int off, int Kp, int lg,
    const float* __restrict__ W, int Nc, int CH,
    int base, int hi, const int* __restrict__ tgtmap,
    float* __restrict__ stats, float* __restrict__ tlog, int ci)
{
  __shared__ float ps[16*256];
  __shared__ float Ws[2600];
  const int tid = threadIdx.x;
  const int r0 = blockIdx.x * 16;
  const int r = tid >> 4, c = tid & 15;
  const int WS = Kp + 4;

  for (int i = tid; i < (16 << lg); i += 256){
    int rr = i >> lg, k = i & (Kp-1);
    ps[rr*256 + k] = packC[(size_t)(r0+rr)*NCAT + off + k];
  }
  const int row = r0 + r;
  int tgt = tgtmap[row];
  int tn = (tgt >= base && tgt < hi) ? tgt - base : -1;

  float mx = -1e30f, sm = 0.f, tl = 0.f;
  for (int n0 = 0; n0 < Nc; n0 += CH){
    int nn = min(CH, Nc - n0);
    __syncthreads();
    for (int i = tid; i < (nn << lg); i += 256){
      int nr = i >> lg, k = i & (Kp-1);
      Ws[nr*WS + k] = W[(size_t)n0*Kp + i];
    }
    __syncthreads();
    for (int n = c; n < nn; n += 16){
      float l = 0.f;
      for (int k = 0; k < Kp; k += 4){
        float4 w4 = *(const float4*)&Ws[n*WS + k];
        l += w4.x*ps[r*256+k] + w4.y*ps[r*256+k+1]
           + w4.z*ps[r*256+k+2] + w4.w*ps[r*256+k+3];
      }
      if (n0 + n == tn) tl = l;
      float nm = fmaxf(mx, l);
      sm = sm*__expf(mx-nm) + __expf(l-nm);
      mx = nm;
    }
  }
  if (tn >= 0 && ((tn & 15) == c) && tl != 0.f) {}   // tl held by one lane
  // merge across the 16 lanes of this row
  for (int o = 8; o; o >>= 1){
    float om = __shfl_down(mx, o, 16);
    float os = __shfl_down(sm, o, 16);
    float nm = fmaxf(mx, om);
    sm = sm*__expf(mx-nm) + os*__expf(om-nm);
    mx = nm;
  }
  if (c == 0){
    stats[(size_t)row*6 + ci*2 + 0] = mx;
    stats[(size_t)row*6 + ci*2 + 1] = sm;
  }
  if (tn >= 0 && (tn & 15) == c) tlog[row] = tl;  // this lane computed n==tn
}

// ---------------- final: head LSE + assemble NLL, reduce ----------------
__global__ __launch_bounds__(256) void k_final(
    const float* __restrict__ packC, const float* __restrict__ stats,
    const float* __restrict__ tlogit, const int* __restrict__ tgtmap,
    float* __restrict__ out)
{
  int row = blockIdx.x*256 + threadIdx.x;
  int tgt = tgtmap[row];
  float nll = 0.f;
  if (tgt != 0){
    const float* hrow = packC + (size_t)row*NCAT;
    float m = hrow[0];
    #pragma unroll
    for (int i=1;i<33;i++) m = fmaxf(m, hrow[i]);
    float s = 0.f;
    #pragma unroll
    for (int i=0;i<33;i++) s += __expf(hrow[i]-m);
    float lse = __logf(s) + m;
    int ci = (tgt>=1000) ? 2 : (tgt>=100) ? 1 : (tgt>=30) ? 0 : -1;
    if (ci < 0){
      nll = lse - hrow[tgt];
    } else {
      float cm = stats[(size_t)row*6 + ci*2 + 0];
      float cs = stats[(size_t)row*6 + ci*2 + 1];
      nll = lse - hrow[30+ci] + (__logf(cs) + cm - tlogit[row]);
    }
  }
  float v = nll;
  for (int off=32; off; off>>=1) v += __shfl_down(v, off);
  __shared__ float wsum[4];
  int lane = threadIdx.x & 63, wv = threadIdx.x >> 6;
  if (lane==0) wsum[wv] = v;
  __syncthreads();
  if (threadIdx.x==0) atomicAdd(out, wsum[0]+wsum[1]+wsum[2]+wsum[3]);
}

extern "C" void kernel_launch(void* const* d_in, const int* in_sizes, int n_in,
                              void* d_out, int out_size, void* d_ws, size_t ws_size,
                              hipStream_t stream)
{
  const float* z      = (const float*)d_in[0];
  const float* emb    = (const float*)d_in[1];
  const float* l2h_w  = (const float*)d_in[2];
  const float* l2h_b  = (const float*)d_in[3];
  const float* w0ih   = (const float*)d_in[4];
  const float* w0hh   = (const float*)d_in[5];
  const float* b0ih   = (const float*)d_in[6];
  const float* b0hh   = (const float*)d_in[7];
  const float* w1ih   = (const float*)d_in[8];
  const float* w1hh   = (const float*)d_in[9];
  const float* b1ih   = (const float*)d_in[10];
  const float* b1hh   = (const float*)d_in[11];
  const float* head_w = (const float*)d_in[12];
  const float* p0     = (const float*)d_in[13];
  const float* tw0    = (const float*)d_in[14];
  const float* p1     = (const float*)d_in[15];
  const float* tw1    = (const float*)d_in[16];
  const float* p2     = (const float*)d_in[17];
  const float* tw2    = (const float*)d_in[18];
  const int* inp_seq  = (const int*)d_in[19];
  const int* tgt_seq  = (const int*)d_in[20];
  const int* length   = (const int*)d_in[21];

  float* ws   = (float*)d_ws;
  ushort* hb0 = (ushort*)ws;                      // 65536 ushorts (h0, both layers)
  ushort* hbP = hb0 + 65536;                      // 65536 ushorts (ping-pong)
  float* bufA = ws + 65536;                       // 8192*1024  pre0 -> h1; later packC etc.
  float* bufB = bufA + (size_t)NROW*HH;           // 8192*1024  pre1 -> h2
  int*   ibuf = (int*)(bufB + (size_t)NROW*HH);
  int* sorted_idx = ibuf;                         // 32
  int* tokmap = ibuf + 32;                        // 8192
  int* tgtmap = tokmap + NROW;                    // 8192
  int* flags  = tgtmap + NROW;                    // 128 ints: ctr L0 @0, ctr L1 @64
  // aliased into bufA once h1 is consumed (after pre1 GEMM):
  float* packC = bufA;                            // 8192*369 = 3,022,848
  float* Bcat  = bufA + 3400000;                  // 369*1024 = 377,856
  float* stats = bufA + 3900000;                  // 8192*6
  float* tlog  = bufA + 3960000;                  // 8192

  float* outF = (float*)d_out;
  hipMemsetAsync(outF, 0, sizeof(float), stream);
  hipMemsetAsync(flags, 0, 128*sizeof(int), stream);

  k_sort<<<1, 32, 0, stream>>>(length, sorted_idx);
  k_maps<<<32, 256, 0, stream>>>(sorted_idx, inp_seq, tgt_seq, tokmap, tgtmap);
  k_hid<<<256, 256, 0, stream>>>(z, l2h_w, l2h_b, hb0);

  // pre0 = emb[tok] @ w0ih^T + b0ih + b0hh
  k_gemm_bf16<<<dim3(HH/128, NROW/128), 256, 0, stream>>>(emb, EE, tokmap, w0ih,
                                                          b0ih, b0hh, bufA, NROW, HH, EE);
  k_rnn_coop<<<NWG, 256, 0, stream>>>(bufA, w0hh, hb0, hbP, flags, 0);      // bufA := h1
  // pre1 = h1 @ w1ih^T + b1ih + b1hh
  k_gemm_bf16<<<dim3(HH/128, NROW/128), 256, 0, stream>>>(bufA, HH, nullptr, w1ih,
                                                          b1ih, b1hh, bufB, NROW, HH, HH);
  k_rnn_coop<<<NWG, 256, 0, stream>>>(bufB, w1hh, hb0, hbP, flags + 64, 1); // bufB := h2

  // pack head+proj weights, then ONE fused GEMM: packC = h2 @ Bcat^T  [8192 x 369]
  k_pack<<<NCAT, 256, 0, stream>>>(head_w, p0, p1, p2, Bcat);
  k_gemm_bf16<<<dim3(3, NROW/128), 256, 0, stream>>>(bufB, HH, nullptr, Bcat,
                                                     nullptr, nullptr, packC, NROW, NCAT, HH);

  // cluster LSEs + target logits (fused)
  k_cluster2<<<NROW/16, 256, 0, stream>>>(packC, 33,  256, 8, tw0, 70,    8,   30,   100,   tgtmap, stats, tlog, 0);
  k_cluster2<<<NROW/16, 256, 0, stream>>>(packC, 289, 64,  6, tw1, 900,   32,  100,  1000,  tgtmap, stats, tlog, 1);
  k_cluster2<<<NROW/16, 256, 0, stream>>>(packC, 353, 16,  4, tw2, 19000, 128, 1000, 20000, tgtmap, stats, tlog, 2);
  k_final<<<NROW/256, 256, 0, stream>>>(packC, stats, tlog, tgtmap, outF);
}